// Round 17
// baseline (202.222 us; speedup 1.0000x reference)
//
#include <hip/hip_runtime.h>

typedef __attribute__((ext_vector_type(8))) short short8;
typedef __attribute__((ext_vector_type(4))) float f32x4;
typedef __attribute__((ext_vector_type(4))) unsigned short u16x4;
typedef __attribute__((ext_vector_type(4))) unsigned int u32x4;

#define MFMA16(a,b,c) __builtin_amdgcn_mfma_f32_16x16x32_bf16((a),(b),(c),0,0,0)

// 0.125 (attn scale) * log2(e), folded into Q at the QKV epilogue.
#define QSCALE 0.1803368801f

__device__ __forceinline__ unsigned short f2bf(float f) {
  unsigned int x = __float_as_uint(f);
  x += 0x7fffu + ((x >> 16) & 1u);
  return (unsigned short)(x >> 16);
}
// async 16B global -> LDS (dest = wave-uniform base + lane*16)
__device__ __forceinline__ void gload16(const unsigned short* g, unsigned short* l) {
  __builtin_amdgcn_global_load_lds(
      (const __attribute__((address_space(1))) unsigned int*)g,
      (__attribute__((address_space(3))) unsigned int*)l, 16, 0, 0);
}
// packed f32x2 -> bf16x2 (lo = a, hi = b), single VALU op
__device__ __forceinline__ unsigned int cvtpk(float a, float b) {
  unsigned int r;
  asm("v_cvt_pk_bf16_f32 %0, %1, %2" : "=v"(r) : "v"(a), "v"(b));
  return r;
}
// raw 2^x (single trans op; OCML exp2f w/o fast-math adds denormal fixup VALU)
__device__ __forceinline__ float fexp2(float x) {
  float r;
  asm("v_exp_f32 %0, %1" : "=v"(r) : "v"(x));
  return r;
}

// Fragment-major layouts (16x16x32 MFMA):
//  A-side (M x K): elem(m,k) -> [((k>>5)*nM16 + (m>>4))*512 + (((k>>3)&3)*16 + (m&15))*8 + (k&7)]
//  B-side (N x K): elem(n,k) -> [((n>>4)*NKB  + (k>>5))*512 + (((k>>3)&3)*16 + (n&15))*8 + (k&7)]
// Either way a wave's fragment is 1KB contiguous: base + lane*16B.

// ---------------------------------------------------------------------------
// Kernel 1: prep = convert x -> A-frag-major bf16 (blocks < 6144) +
//                  build LoRA-folded weights in B-FRAG-MAJOR (rest).
// ---------------------------------------------------------------------------
__global__ __launch_bounds__(256) void prep(
    const float* __restrict__ x,
    const float* __restrict__ w_qkv,
    const float* __restrict__ w_proj,
    const float* __restrict__ q_a, const float* __restrict__ q_b,
    const float* __restrict__ k_a, const float* __restrict__ k_b,
    const float* __restrict__ v_a, const float* __restrict__ v_b,
    const float* __restrict__ o_a, const float* __restrict__ o_b,
    unsigned short* __restrict__ xf,
    unsigned short* __restrict__ wqkv_eff,
    unsigned short* __restrict__ wproj_eff)
{
  int bid = blockIdx.x;
  if (bid < 6144) {
    int i4 = (bid * 256 + threadIdx.x) * 4;
    int m  = i4 / 768;
    int k4 = i4 - m * 768;             // 4 consecutive k, same 8-chunk half
    f32x4 v = *(const f32x4*)&x[i4];
    u16x4 o;
    o.x = f2bf(v.x); o.y = f2bf(v.y); o.z = f2bf(v.z); o.w = f2bf(v.w);
    int kb = k4 >> 5, qd = (k4 >> 3) & 3, j0 = k4 & 7;
    size_t idx = ((size_t)(kb * 512 + (m >> 4)) << 9) +
                 (((qd << 4) + (m & 15)) << 3) + j0;
    *(u16x4*)&xf[idx] = o;
    return;
  }
  const int QKV = 2304 * 768;
  int idx = (bid - 6144) * 256 + threadIdx.x;
  if (idx < QKV) {
    int n = idx / 768, c = idx - n * 768;
    int sec = n / 768;
    int nr = n - sec * 768;
    const float* a; const float* b;
    if (sec == 0)      { a = q_a; b = q_b; }
    else if (sec == 1) { a = k_a; b = k_b; }
    else               { a = v_a; b = v_b; }
    float acc = w_qkv[idx];
    #pragma unroll
    for (int r = 0; r < 8; r++)
      acc += b[nr * 8 + r] * a[r * 768 + c];
    // B-frag-major (NKB = 768/32 = 24)
    size_t widx = ((size_t)((n >> 4) * 24 + (c >> 5)) << 9) +
                  ((((c >> 3) & 3) * 16 + (n & 15)) << 3) + (c & 7);
    wqkv_eff[widx] = f2bf(acc);
  } else {
    int i2 = idx - QKV;
    int n = i2 / 768, c = i2 - n * 768;
    float acc = w_proj[i2];
    #pragma unroll
    for (int r = 0; r < 8; r++)
      acc += o_b[n * 8 + r] * o_a[r * 768 + c];
    size_t widx = ((size_t)((n >> 4) * 24 + (c >> 5)) << 9) +
                  ((((c >> 3) & 3) * 16 + (n & 15)) << 3) + (c & 7);
    wproj_eff[widx] = f2bf(acc);
  }
}

// ---------------------------------------------------------------------------
// Kernel 2/4: C[M,Ncols] = A@W^T + bias. A in A-FRAG-MAJOR (direct
// global->register, prefetched one chunk ahead).  W in B-FRAG-MAJOR, staged
// per 64-K chunk via gload16 into double-buffered LDS.  Runtime-K loop
// (R16: full unroll regressed).
// Round-17: BN 64 -> 96.  Old QKV grid (64,36) = 2304 blocks = 9/CU, but
// 9 x 256 threads > 2048/CU cap -> at most 8 resident -> 8+1 two-round tail
// (same disease as attn's R13 5+1 tail, fixed for -6us).  BN=96: grid
// (64,24) = 1536 = 6/CU single round; 48 MFMA/barrier (was 32); W chunk
// 12KB x 2 = 24KB LDS (6 x 24 = 144 <= 160).  acc[2][6] -> VGPR ~80-90;
// need <= 85 for 6 waves/SIMD (failure signature: VGPR > 85 in counters ->
// 5/CU tail returns -> revert).  Epilogue: cb = n0%768 + j*16; h = cb>>6;
// d = (cb&63) + l16 (cb&63 in {0,16,32,48}, l16<16 -> no head crossing;
// 768 = 8*96 -> section uniform per block).
// mode 0 (QKV): Q*QSCALE -> q[BH][N][64] row-major;
//               K -> A-FRAG-MAJOR per bh; V -> B-FRAG-MAJOR per bh with the
//               swapped-QK^T key perm folded (see attn).
// mode 1: fp32 row-major store (final output).
// ---------------------------------------------------------------------------
__global__ __launch_bounds__(256) void gemm_bt(
    const unsigned short* __restrict__ Af,
    const unsigned short* __restrict__ Wf,
    const float* __restrict__ bias,
    unsigned short* __restrict__ out0,
    unsigned short* __restrict__ out1,
    unsigned short* __restrict__ out2,
    float* __restrict__ outf,
    int K, int Ncols, int mode)
{
  __shared__ alignas(16) unsigned short Wl[2][6144];   // 2 x 12 KB W chunk (6 n-tiles)
  const int tid  = threadIdx.x;
  const int wave = tid >> 6;
  const int lane = tid & 63;
  const int quad = lane >> 4;
  const int l16  = lane & 15;
  const int m0 = blockIdx.x * 128;
  const int n0 = blockIdx.y * 96;

  const int M16b = (m0 >> 4) + wave * 2;       // wave's row-tiles: M16b, M16b+1
  const int nt0 = n0 >> 4;                     // 6 n-tiles per block
  const int NKB = K >> 5;                      // k-blocks in W frag layout

  // prologue: stage W chunk 0 (12 frags; wave w stages frags w, 4+w, 8+w)
  #pragma unroll
  for (int a = 0; a < 3; a++) {
    const int i = a * 4 + wave;                // frag i -> (nt = i>>1, ks = i&1)
    gload16(Wf + ((size_t)((nt0 + (i >> 1)) * NKB + (i & 1)) << 9) + (lane << 3),
            &Wl[0][(i << 9) + (lane << 3)]);
  }

  short8 aCur[2][2], aNxt[2][2] = {};          // [row-tile t][ks]
  #pragma unroll
  for (int t = 0; t < 2; t++)
    #pragma unroll
    for (int ks = 0; ks < 2; ks++)
      aCur[t][ks] = *(const short8*)&Af[((size_t)(ks * 512 + M16b + t) << 9) + (lane << 3)];

  f32x4 acc[2][6] = {};
  const int nkc = K >> 6;

  for (int kc = 0; kc < nkc; kc++) {
    const int p = kc & 1;
    __syncthreads();   // implicit vmcnt(0): chunk [p] staged; all waves done with [1-p]
    if (kc + 1 < nkc) {
      #pragma unroll
      for (int a = 0; a < 3; a++) {
        const int i = a * 4 + wave;
        gload16(Wf + ((size_t)((nt0 + (i >> 1)) * NKB + (kc + 1) * 2 + (i & 1)) << 9) + (lane << 3),
                &Wl[1 - p][(i << 9) + (lane << 3)]);
      }
      const int kbn = (kc + 1) * 2;
      #pragma unroll
      for (int t = 0; t < 2; t++)
        #pragma unroll
        for (int ks = 0; ks < 2; ks++)
          aNxt[t][ks] = *(const short8*)&Af[((size_t)((kbn + ks) * 512 + M16b + t) << 9) + (lane << 3)];
    }
    #pragma unroll
    for (int ks = 0; ks < 2; ks++) {
      #pragma unroll
      for (int nt = 0; nt < 6; nt++) {
        short8 bf = *(const short8*)&Wl[p][((nt * 2 + ks) << 9) + (lane << 3)];
        acc[0][nt] = MFMA16(aCur[0][ks], bf, acc[0][nt]);
        acc[1][nt] = MFMA16(aCur[1][ks], bf, acc[1][nt]);
      }
    }
    #pragma unroll
    for (int t = 0; t < 2; t++)
      #pragma unroll
      for (int ks = 0; ks < 2; ks++)
        aCur[t][ks] = aNxt[t][ks];
  }

  float bv[6];
  #pragma unroll
  for (int j = 0; j < 6; j++) bv[j] = bias[n0 + j * 16 + l16];

  if (mode == 0) {
    const int sec = n0 / 768;                  // uniform: 768 % 96 == 0
    const int cb0 = n0 % 768;
    unsigned short* dst = (sec == 0) ? out0 : ((sec == 1) ? out1 : out2);
    const float scl = (sec == 0) ? QSCALE : 1.0f;
    #pragma unroll
    for (int rg = 0; rg < 2; rg++) {
      #pragma unroll
      for (int r = 0; r < 4; r++) {
        int m  = m0 + wave * 32 + rg * 16 + quad * 4 + r;
        int b  = m >> 10, np = m & 1023;
        // within-64 key slot for the swapped-QK^T in-register P (V path)
        int s = (np & 35) | ((np & 12) << 1) | ((np & 16) >> 2);
        #pragma unroll
        for (int j = 0; j < 6; j++) {
          int cb = cb0 + j * 16;
          int h  = cb >> 6;
          int bh = b * 12 + h;
          int d  = (cb & 63) + l16;
          float v = (acc[rg][j][r] + bv[j]) * scl;
          if (sec == 0) {
            dst[((size_t)bh << 16) + ((size_t)np << 6) + d] = f2bf(v);
          } else if (sec == 1) {
            // K A-frag-major
            size_t kidx = ((size_t)((np >> 4) * 2 + (d >> 5)) << 9) +
                          ((((d >> 3) & 3) * 16 + (np & 15)) << 3) + (d & 7);
            dst[((size_t)bh << 16) + kidx] = f2bf(v);
          } else {
            // V B-frag-major, key perm folded
            size_t vidx = ((size_t)(((np >> 6) * 2 + (s >> 5)) * 4 + (d >> 4)) << 9) +
                          ((((s >> 3) & 3) * 16 + (d & 15)) << 3) + (s & 7);
            dst[((size_t)bh << 16) + vidx] = f2bf(v);
          }
        }
      }
    }
  } else {
    #pragma unroll
    for (int rg = 0; rg < 2; rg++) {
      #pragma unroll
      for (int r = 0; r < 4; r++) {
        int m = m0 + wave * 32 + rg * 16 + quad * 4 + r;
        #pragma unroll
        for (int j = 0; j < 6; j++)
          outf[(size_t)m * Ncols + n0 + j * 16 + l16] = acc[rg][j][r] + bv[j];
      }
    }
  }
}

// ---------------------------------------------------------------------------
// Kernel 3: flash attention (UNCHANGED from R16 best config).  SWAPPED QK^T,
// frag-major K/V; LDS 24KB (K single 8KB + V double 16KB) -> 6 blocks/CU,
// one dispatch round.  Per kt (2 x __syncthreads):
//   A: publish K(kt),V(kt) -> QK from Ks -> B: QK reads retired ->
//   stage K(kt+1)->Ks, V(kt+1)->Vs[1-p] -> softmax (regs) -> PV from Vs[p]
// exp2 via raw v_exp_f32; kt loop fully unrolled (static buffer parity).
// QBLK=64, grid 96x16.  Row-sum denominator via ones-column MFMA.
// ---------------------------------------------------------------------------
__global__ __launch_bounds__(256) void attn(
    const unsigned short* __restrict__ q,
    const unsigned short* __restrict__ k,
    const unsigned short* __restrict__ vt,
    unsigned short* __restrict__ of)
{
  __shared__ alignas(16) unsigned short Ks[4096];      // 8 KB, single buffer
  __shared__ alignas(16) unsigned short Vs2[2][4096];  // 2 x 8 KB
  const int tid  = threadIdx.x;
  const int wave = tid >> 6;
  const int lane = tid & 63;
  const int quad = lane >> 4;
  const int l16  = lane & 15;
  const int bh = blockIdx.x;
  const int q0 = blockIdx.y * 64;
  const unsigned short* qb = q  + ((size_t)bh << 16);
  const unsigned short* kb = k  + ((size_t)bh << 16);
  const unsigned short* vb = vt + ((size_t)bh << 16);

  const int t8 = tid * 8;
  // prologue: stage K(0) and V(0)
  gload16(kb + t8,        &Ks[t8]);
  gload16(kb + 2048 + t8, &Ks[2048 + t8]);
  gload16(vb + t8,        &Vs2[0][t8]);
  gload16(vb + 2048 + t8, &Vs2[0][2048 + t8]);

  // Q B-frags direct from global: B[n=l16][kdim = ks*32 + quad*8 + j]
  short8 bq[2];
  #pragma unroll
  for (int ks = 0; ks < 2; ks++)
    bq[ks] = *(const short8*)&qb[((size_t)(q0 + wave * 16 + l16) << 6) +
                                 ks * 32 + quad * 8];

  // all-ones bf16 B-fragment for the row-sum MFMA
  union { u32x4 w; short8 h; } onesu;
  onesu.w.x = 0x3F803F80u; onesu.w.y = 0x3F803F80u;
  onesu.w.z = 0x3F803F80u; onesu.w.w = 0x3F803F80u;
  const short8 onesb = onesu.h;

  f32x4 Oacc[4] = {};
  f32x4 lacc = {};

  union PAW { u32x4 w; short8 h; };

  #pragma unroll
  for (int kt = 0; kt < 16; kt++) {
    const int p = kt & 1;
    __syncthreads();   // A: K(kt) and V(kt) published (own-wave vmcnt drain)

    // QK^T swapped: A = K frag (LDS single buffer), B = Q (regs).
    f32x4 s[4] = {};
    #pragma unroll
    for (int ks = 0; ks < 2; ks++) {
      const unsigned short* lk = &Ks[ks * 512 + lane * 8];
      short8 a0 = *(const short8*)&lk[0];
      short8 a1 = *(const short8*)&lk[1024];
      short8 a2 = *(const short8*)&lk[2048];
      short8 a3 = *(const short8*)&lk[3072];
      s[0] = MFMA16(a0, bq[ks], s[0]);
      s[1] = MFMA16(a1, bq[ks], s[1]);
      s[2] = MFMA16(a2, bq[ks], s[2]);
      s[3] = MFMA16(a3, bq[ks], s[3]);
    }

    __syncthreads();   // B: all waves' QK reads of Ks retired
    if (kt < 15) {
      const unsigned short* gkn = kb + (kt + 1) * 4096 + t8;
      const unsigned short* gvn = vb + (kt + 1) * 4096 + t8;
      gload16(gkn,        &Ks[t8]);
      gload16(gkn + 2048, &Ks[2048 + t8]);
      gload16(gvn,        &Vs2[1 - p][t8]);
      gload16(gvn + 2048, &Vs2[1 - p][2048 + t8]);
    }

    // softmax (no max-subtraction; scale folded into Q) + in-register P frags
    f32x4 e[4];
    #pragma unroll
    for (int i = 0; i < 4; i++) {
      e[i].x = fexp2(s[i].x);
      e[i].y = fexp2(s[i].y);
      e[i].z = fexp2(s[i].z);
      e[i].w = fexp2(s[i].w);
    }
    short8 pa[2];
    #pragma unroll
    for (int ks = 0; ks < 2; ks++) {
      PAW pw;
      pw.w.x = cvtpk(e[2 * ks].x,     e[2 * ks].y);
      pw.w.y = cvtpk(e[2 * ks].z,     e[2 * ks].w);
      pw.w.z = cvtpk(e[2 * ks + 1].x, e[2 * ks + 1].y);
      pw.w.w = cvtpk(e[2 * ks + 1].z, e[2 * ks + 1].w);
      pa[ks] = pw.h;
    }

    // PV: A = P frags (regs), B = V frag (LDS, lane-contiguous).
    #pragma unroll
    for (int ks = 0; ks < 2; ks++) {
      const unsigned short* lv = &Vs2[p][ks * 2048 + lane * 8];
      short8 v0 = *(const short8*)&lv[0];
      short8 v1 = *(const short8*)&lv[512];
      short8 v2 = *(const short8*)&lv[1024];
      short8 v3 = *(const short8*)&lv[1536];
      Oacc[0] = MFMA16(pa[ks], v0, Oacc[0]);
      Oacc[1] = MFMA16(pa[ks], v1, Oacc[1]);
      Oacc[2] = MFMA16(pa[ks], v2, Oacc[2]);
      Oacc[3] = MFMA16(pa[ks], v3, Oacc[3]);
      lacc    = MFMA16(pa[ks], onesb, lacc);
    }
  }

  // lacc[r] = full row sum for q-row quad*4+r; O store in A-FRAG-MAJOR
  // (proj GEMM's A-path).
  const int b = bh / 12, h = bh - (bh / 12) * 12;
  #pragma unroll
  for (int r = 0; r < 4; r++) {
    float inv = 1.0f / lacc[r];
    int np  = q0 + wave * 16 + quad * 4 + r;
    int M16 = b * 64 + (np >> 4);
    int l16m = np & 15;
    #pragma unroll
    for (int j = 0; j < 4; j++) {
      int col = h * 64 + j * 16 + l16;
      int kb2 = col >> 5;
      int qc  = (col >> 3) & 3;
      size_t idx = ((size_t)(kb2 * 512 + M16) << 9) +
                   ((qc * 16 + l16m) << 3) + (l16 & 7);
      of[idx] = f2bf(Oacc[j][r] * inv);
    }
  }
}

// ---------------------------------------------------------------------------
extern "C" void kernel_launch(void* const* d_in, const int* in_sizes, int n_in,
                              void* d_out, int out_size, void* d_ws, size_t ws_size,
                              hipStream_t stream) {
  const float* x      = (const float*)d_in[0];
  const float* w_qkv  = (const float*)d_in[1];
  const float* b_qkv  = (const float*)d_in[2];
  const float* w_proj = (const float*)d_in[3];
  const float* b_proj = (const float*)d_in[4];
  const float* q_a    = (const float*)d_in[5];
  const float* q_b    = (const float*)d_in[6];
  const float* k_a    = (const float*)d_in[7];
  const float* k_b    = (const float*)d_in[8];
  const float* v_a    = (const float*)d_in[9];
  const float* v_b    = (const float*)d_in[10];
  const float* o_a    = (const float*)d_in[11];
  const float* o_b    = (const float*)d_in[12];

  char* ws = (char*)d_ws;
  unsigned short* wqkv_eff  = (unsigned short*)(ws + 0);          // 3,538,944
  unsigned short* wproj_eff = (unsigned short*)(ws + 3538944);    // 1,179,648
  unsigned short* xf        = (unsigned short*)(ws + 4718592);    // 12,582,912 (A-frag-major; reused as of)
  unsigned short* qd        = (unsigned short*)(ws + 17301504);   // 12,582,912
  unsigned short* kd        = (unsigned short*)(ws + 29884416);   // 12,582,912
  unsigned short* vtd       = (unsigned short*)(ws + 42467328);   // 12,582,912 (end 55,050,240)
  unsigned short* of        = xf;  // xf dead after QKV GEMM

  prep<<<dim3(6144 + 9216), dim3(256), 0, stream>>>(
      x, w_qkv, w_proj, q_a, q_b, k_a, k_b, v_a, v_b, o_a, o_b,
      xf, wqkv_eff, wproj_eff);

  gemm_bt<<<dim3(64, 24), dim3(256), 0, stream>>>(
      xf, wqkv_eff, b_qkv, qd, kd, vtd, nullptr, 768, 2304, 0);

  attn<<<dim3(96, 16), dim3(256), 0, stream>>>(qd, kd, vtd, of);

  gemm_bt<<<dim3(64, 8), dim3(256), 0, stream>>>(
      of, wproj_eff, b_proj, nullptr, nullptr, nullptr, (float*)d_out, 768, 768, 1);
}

// Round 18
// 191.574 us; speedup vs baseline: 1.0556x; 1.0556x over previous
//
#include <hip/hip_runtime.h>

typedef __attribute__((ext_vector_type(8))) short short8;
typedef __attribute__((ext_vector_type(4))) float f32x4;
typedef __attribute__((ext_vector_type(4))) unsigned short u16x4;
typedef __attribute__((ext_vector_type(4))) unsigned int u32x4;

#define MFMA16(a,b,c) __builtin_amdgcn_mfma_f32_16x16x32_bf16((a),(b),(c),0,0,0)

// 0.125 (attn scale) * log2(e), folded into Q at the QKV epilogue.
#define QSCALE 0.1803368801f

__device__ __forceinline__ unsigned short f2bf(float f) {
  unsigned int x = __float_as_uint(f);
  x += 0x7fffu + ((x >> 16) & 1u);
  return (unsigned short)(x >> 16);
}
// async 16B global -> LDS (dest = wave-uniform base + lane*16)
__device__ __forceinline__ void gload16(const unsigned short* g, unsigned short* l) {
  __builtin_amdgcn_global_load_lds(
      (const __attribute__((address_space(1))) unsigned int*)g,
      (__attribute__((address_space(3))) unsigned int*)l, 16, 0, 0);
}
// packed f32x2 -> bf16x2 (lo = a, hi = b), single VALU op
__device__ __forceinline__ unsigned int cvtpk(float a, float b) {
  unsigned int r;
  asm("v_cvt_pk_bf16_f32 %0, %1, %2" : "=v"(r) : "v"(a), "v"(b));
  return r;
}
// raw 2^x (single trans op; OCML exp2f w/o fast-math adds denormal fixup VALU)
__device__ __forceinline__ float fexp2(float x) {
  float r;
  asm("v_exp_f32 %0, %1" : "=v"(r) : "v"(x));
  return r;
}

// Fragment-major layouts (16x16x32 MFMA):
//  A-side (M x K): elem(m,k) -> [((k>>5)*nM16 + (m>>4))*512 + (((k>>3)&3)*16 + (m&15))*8 + (k&7)]
//  B-side (N x K): elem(n,k) -> [((n>>4)*NKB  + (k>>5))*512 + (((k>>3)&3)*16 + (n&15))*8 + (k&7)]
// Either way a wave's fragment is 1KB contiguous: base + lane*16B.

// ---------------------------------------------------------------------------
// Kernel 1: prep = convert x -> A-frag-major bf16 (blocks < 6144) +
//                  build LoRA-folded weights in B-FRAG-MAJOR (rest).
// ---------------------------------------------------------------------------
__global__ __launch_bounds__(256) void prep(
    const float* __restrict__ x,
    const float* __restrict__ w_qkv,
    const float* __restrict__ w_proj,
    const float* __restrict__ q_a, const float* __restrict__ q_b,
    const float* __restrict__ k_a, const float* __restrict__ k_b,
    const float* __restrict__ v_a, const float* __restrict__ v_b,
    const float* __restrict__ o_a, const float* __restrict__ o_b,
    unsigned short* __restrict__ xf,
    unsigned short* __restrict__ wqkv_eff,
    unsigned short* __restrict__ wproj_eff)
{
  int bid = blockIdx.x;
  if (bid < 6144) {
    int i4 = (bid * 256 + threadIdx.x) * 4;
    int m  = i4 / 768;
    int k4 = i4 - m * 768;             // 4 consecutive k, same 8-chunk half
    f32x4 v = *(const f32x4*)&x[i4];
    u16x4 o;
    o.x = f2bf(v.x); o.y = f2bf(v.y); o.z = f2bf(v.z); o.w = f2bf(v.w);
    int kb = k4 >> 5, qd = (k4 >> 3) & 3, j0 = k4 & 7;
    size_t idx = ((size_t)(kb * 512 + (m >> 4)) << 9) +
                 (((qd << 4) + (m & 15)) << 3) + j0;
    *(u16x4*)&xf[idx] = o;
    return;
  }
  const int QKV = 2304 * 768;
  int idx = (bid - 6144) * 256 + threadIdx.x;
  if (idx < QKV) {
    int n = idx / 768, c = idx - n * 768;
    int sec = n / 768;
    int nr = n - sec * 768;
    const float* a; const float* b;
    if (sec == 0)      { a = q_a; b = q_b; }
    else if (sec == 1) { a = k_a; b = k_b; }
    else               { a = v_a; b = v_b; }
    float acc = w_qkv[idx];
    #pragma unroll
    for (int r = 0; r < 8; r++)
      acc += b[nr * 8 + r] * a[r * 768 + c];
    // B-frag-major (NKB = 768/32 = 24)
    size_t widx = ((size_t)((n >> 4) * 24 + (c >> 5)) << 9) +
                  ((((c >> 3) & 3) * 16 + (n & 15)) << 3) + (c & 7);
    wqkv_eff[widx] = f2bf(acc);
  } else {
    int i2 = idx - QKV;
    int n = i2 / 768, c = i2 - n * 768;
    float acc = w_proj[i2];
    #pragma unroll
    for (int r = 0; r < 8; r++)
      acc += o_b[n * 8 + r] * o_a[r * 768 + c];
    size_t widx = ((size_t)((n >> 4) * 24 + (c >> 5)) << 9) +
                  ((((c >> 3) & 3) * 16 + (n & 15)) << 3) + (c & 7);
    wproj_eff[widx] = f2bf(acc);
  }
}

// ---------------------------------------------------------------------------
// Kernel 2/4: C[M,Ncols] = A@W^T + bias. A in A-FRAG-MAJOR (direct
// global->register, prefetched one chunk ahead).  W in B-FRAG-MAJOR, staged
// per 64-K chunk via gload16 into double-buffered LDS.  Runtime-K loop.
// Round-18: BN is a TEMPLATE PARAM -- tile/grid shape coupling measured in
// R17: BN=96 on QKV (grid (64,24) = 6/CU single round, 48 MFMA/barrier) =
// 46.5us measured; but BN=96 on proj dropped its grid to (64,8) = 2/CU =
// 8 waves/CU, latency-starved (+7us total).  QKV uses BN=96, proj BN=64
// (grid (64,12) = 3/CU, its measured-good shape).
// Epilogue (generic over BN | 768%BN==0): cb = n0%768 + j*16; h = cb>>6;
// d = (cb&63) + l16  (cb&63 multiple of 16, l16<16 -> no head crossing).
// mode 0 (QKV): Q*QSCALE -> q[BH][N][64] row-major;
//               K -> A-FRAG-MAJOR per bh; V -> B-FRAG-MAJOR per bh with the
//               swapped-QK^T key perm folded (see attn).
// mode 1: fp32 row-major store (final output).
// ---------------------------------------------------------------------------
template <int BN>
__global__ __launch_bounds__(256) void gemm_bt(
    const unsigned short* __restrict__ Af,
    const unsigned short* __restrict__ Wf,
    const float* __restrict__ bias,
    unsigned short* __restrict__ out0,
    unsigned short* __restrict__ out1,
    unsigned short* __restrict__ out2,
    float* __restrict__ outf,
    int K, int Ncols, int mode)
{
  constexpr int NT = BN >> 4;                  // n-tiles per block
  __shared__ alignas(16) unsigned short Wl[2][NT * 1024];  // 2 x (NT*2KB) W chunk
  const int tid  = threadIdx.x;
  const int wave = tid >> 6;
  const int lane = tid & 63;
  const int quad = lane >> 4;
  const int l16  = lane & 15;
  const int m0 = blockIdx.x * 128;
  const int n0 = blockIdx.y * BN;

  const int M16b = (m0 >> 4) + wave * 2;       // wave's row-tiles: M16b, M16b+1
  const int nt0 = n0 >> 4;
  const int NKB = K >> 5;                      // k-blocks in W frag layout

  // prologue: stage W chunk 0 (2*NT frags; wave w stages frags a*4+w)
  #pragma unroll
  for (int a = 0; a < NT / 2; a++) {
    const int i = a * 4 + wave;                // frag i -> (nt = i>>1, ks = i&1)
    gload16(Wf + ((size_t)((nt0 + (i >> 1)) * NKB + (i & 1)) << 9) + (lane << 3),
            &Wl[0][(i << 9) + (lane << 3)]);
  }

  short8 aCur[2][2], aNxt[2][2] = {};          // [row-tile t][ks]
  #pragma unroll
  for (int t = 0; t < 2; t++)
    #pragma unroll
    for (int ks = 0; ks < 2; ks++)
      aCur[t][ks] = *(const short8*)&Af[((size_t)(ks * 512 + M16b + t) << 9) + (lane << 3)];

  f32x4 acc[2][NT] = {};
  const int nkc = K >> 6;

  for (int kc = 0; kc < nkc; kc++) {
    const int p = kc & 1;
    __syncthreads();   // implicit vmcnt(0): chunk [p] staged; all waves done with [1-p]
    if (kc + 1 < nkc) {
      #pragma unroll
      for (int a = 0; a < NT / 2; a++) {
        const int i = a * 4 + wave;
        gload16(Wf + ((size_t)((nt0 + (i >> 1)) * NKB + (kc + 1) * 2 + (i & 1)) << 9) + (lane << 3),
                &Wl[1 - p][(i << 9) + (lane << 3)]);
      }
      const int kbn = (kc + 1) * 2;
      #pragma unroll
      for (int t = 0; t < 2; t++)
        #pragma unroll
        for (int ks = 0; ks < 2; ks++)
          aNxt[t][ks] = *(const short8*)&Af[((size_t)((kbn + ks) * 512 + M16b + t) << 9) + (lane << 3)];
    }
    #pragma unroll
    for (int ks = 0; ks < 2; ks++) {
      #pragma unroll
      for (int nt = 0; nt < NT; nt++) {
        short8 bf = *(const short8*)&Wl[p][((nt * 2 + ks) << 9) + (lane << 3)];
        acc[0][nt] = MFMA16(aCur[0][ks], bf, acc[0][nt]);
        acc[1][nt] = MFMA16(aCur[1][ks], bf, acc[1][nt]);
      }
    }
    #pragma unroll
    for (int t = 0; t < 2; t++)
      #pragma unroll
      for (int ks = 0; ks < 2; ks++)
        aCur[t][ks] = aNxt[t][ks];
  }

  float bv[NT];
  #pragma unroll
  for (int j = 0; j < NT; j++) bv[j] = bias[n0 + j * 16 + l16];

  if (mode == 0) {
    const int sec = n0 / 768;                  // uniform: 768 % BN == 0
    const int cb0 = n0 % 768;
    unsigned short* dst = (sec == 0) ? out0 : ((sec == 1) ? out1 : out2);
    const float scl = (sec == 0) ? QSCALE : 1.0f;
    #pragma unroll
    for (int rg = 0; rg < 2; rg++) {
      #pragma unroll
      for (int r = 0; r < 4; r++) {
        int m  = m0 + wave * 32 + rg * 16 + quad * 4 + r;
        int b  = m >> 10, np = m & 1023;
        // within-64 key slot for the swapped-QK^T in-register P (V path)
        int s = (np & 35) | ((np & 12) << 1) | ((np & 16) >> 2);
        #pragma unroll
        for (int j = 0; j < NT; j++) {
          int cb = cb0 + j * 16;
          int h  = cb >> 6;
          int bh = b * 12 + h;
          int d  = (cb & 63) + l16;
          float v = (acc[rg][j][r] + bv[j]) * scl;
          if (sec == 0) {
            dst[((size_t)bh << 16) + ((size_t)np << 6) + d] = f2bf(v);
          } else if (sec == 1) {
            // K A-frag-major
            size_t kidx = ((size_t)((np >> 4) * 2 + (d >> 5)) << 9) +
                          ((((d >> 3) & 3) * 16 + (np & 15)) << 3) + (d & 7);
            dst[((size_t)bh << 16) + kidx] = f2bf(v);
          } else {
            // V B-frag-major, key perm folded
            size_t vidx = ((size_t)(((np >> 6) * 2 + (s >> 5)) * 4 + (d >> 4)) << 9) +
                          ((((s >> 3) & 3) * 16 + (d & 15)) << 3) + (s & 7);
            dst[((size_t)bh << 16) + vidx] = f2bf(v);
          }
        }
      }
    }
  } else {
    #pragma unroll
    for (int rg = 0; rg < 2; rg++) {
      #pragma unroll
      for (int r = 0; r < 4; r++) {
        int m = m0 + wave * 32 + rg * 16 + quad * 4 + r;
        #pragma unroll
        for (int j = 0; j < NT; j++)
          outf[(size_t)m * Ncols + n0 + j * 16 + l16] = acc[rg][j][r] + bv[j];
      }
    }
  }
}

// ---------------------------------------------------------------------------
// Kernel 3: flash attention (UNCHANGED -- best config).  SWAPPED QK^T,
// frag-major K/V; LDS 24KB (K single 8KB + V double 16KB) -> 6 blocks/CU,
// one dispatch round.  Per kt (2 x __syncthreads):
//   A: publish K(kt),V(kt) -> QK from Ks -> B: QK reads retired ->
//   stage K(kt+1)->Ks, V(kt+1)->Vs[1-p] -> softmax (regs) -> PV from Vs[p]
// exp2 via raw v_exp_f32; kt loop fully unrolled (static buffer parity).
// QBLK=64, grid 96x16.  Row-sum denominator via ones-column MFMA.
// ---------------------------------------------------------------------------
__global__ __launch_bounds__(256) void attn(
    const unsigned short* __restrict__ q,
    const unsigned short* __restrict__ k,
    const unsigned short* __restrict__ vt,
    unsigned short* __restrict__ of)
{
  __shared__ alignas(16) unsigned short Ks[4096];      // 8 KB, single buffer
  __shared__ alignas(16) unsigned short Vs2[2][4096];  // 2 x 8 KB
  const int tid  = threadIdx.x;
  const int wave = tid >> 6;
  const int lane = tid & 63;
  const int quad = lane >> 4;
  const int l16  = lane & 15;
  const int bh = blockIdx.x;
  const int q0 = blockIdx.y * 64;
  const unsigned short* qb = q  + ((size_t)bh << 16);
  const unsigned short* kb = k  + ((size_t)bh << 16);
  const unsigned short* vb = vt + ((size_t)bh << 16);

  const int t8 = tid * 8;
  // prologue: stage K(0) and V(0)
  gload16(kb + t8,        &Ks[t8]);
  gload16(kb + 2048 + t8, &Ks[2048 + t8]);
  gload16(vb + t8,        &Vs2[0][t8]);
  gload16(vb + 2048 + t8, &Vs2[0][2048 + t8]);

  // Q B-frags direct from global: B[n=l16][kdim = ks*32 + quad*8 + j]
  short8 bq[2];
  #pragma unroll
  for (int ks = 0; ks < 2; ks++)
    bq[ks] = *(const short8*)&qb[((size_t)(q0 + wave * 16 + l16) << 6) +
                                 ks * 32 + quad * 8];

  // all-ones bf16 B-fragment for the row-sum MFMA
  union { u32x4 w; short8 h; } onesu;
  onesu.w.x = 0x3F803F80u; onesu.w.y = 0x3F803F80u;
  onesu.w.z = 0x3F803F80u; onesu.w.w = 0x3F803F80u;
  const short8 onesb = onesu.h;

  f32x4 Oacc[4] = {};
  f32x4 lacc = {};

  union PAW { u32x4 w; short8 h; };

  #pragma unroll
  for (int kt = 0; kt < 16; kt++) {
    const int p = kt & 1;
    __syncthreads();   // A: K(kt) and V(kt) published (own-wave vmcnt drain)

    // QK^T swapped: A = K frag (LDS single buffer), B = Q (regs).
    f32x4 s[4] = {};
    #pragma unroll
    for (int ks = 0; ks < 2; ks++) {
      const unsigned short* lk = &Ks[ks * 512 + lane * 8];
      short8 a0 = *(const short8*)&lk[0];
      short8 a1 = *(const short8*)&lk[1024];
      short8 a2 = *(const short8*)&lk[2048];
      short8 a3 = *(const short8*)&lk[3072];
      s[0] = MFMA16(a0, bq[ks], s[0]);
      s[1] = MFMA16(a1, bq[ks], s[1]);
      s[2] = MFMA16(a2, bq[ks], s[2]);
      s[3] = MFMA16(a3, bq[ks], s[3]);
    }

    __syncthreads();   // B: all waves' QK reads of Ks retired
    if (kt < 15) {
      const unsigned short* gkn = kb + (kt + 1) * 4096 + t8;
      const unsigned short* gvn = vb + (kt + 1) * 4096 + t8;
      gload16(gkn,        &Ks[t8]);
      gload16(gkn + 2048, &Ks[2048 + t8]);
      gload16(gvn,        &Vs2[1 - p][t8]);
      gload16(gvn + 2048, &Vs2[1 - p][2048 + t8]);
    }

    // softmax (no max-subtraction; scale folded into Q) + in-register P frags
    f32x4 e[4];
    #pragma unroll
    for (int i = 0; i < 4; i++) {
      e[i].x = fexp2(s[i].x);
      e[i].y = fexp2(s[i].y);
      e[i].z = fexp2(s[i].z);
      e[i].w = fexp2(s[i].w);
    }
    short8 pa[2];
    #pragma unroll
    for (int ks = 0; ks < 2; ks++) {
      PAW pw;
      pw.w.x = cvtpk(e[2 * ks].x,     e[2 * ks].y);
      pw.w.y = cvtpk(e[2 * ks].z,     e[2 * ks].w);
      pw.w.z = cvtpk(e[2 * ks + 1].x, e[2 * ks + 1].y);
      pw.w.w = cvtpk(e[2 * ks + 1].z, e[2 * ks + 1].w);
      pa[ks] = pw.h;
    }

    // PV: A = P frags (regs), B = V frag (LDS, lane-contiguous).
    #pragma unroll
    for (int ks = 0; ks < 2; ks++) {
      const unsigned short* lv = &Vs2[p][ks * 2048 + lane * 8];
      short8 v0 = *(const short8*)&lv[0];
      short8 v1 = *(const short8*)&lv[512];
      short8 v2 = *(const short8*)&lv[1024];
      short8 v3 = *(const short8*)&lv[1536];
      Oacc[0] = MFMA16(pa[ks], v0, Oacc[0]);
      Oacc[1] = MFMA16(pa[ks], v1, Oacc[1]);
      Oacc[2] = MFMA16(pa[ks], v2, Oacc[2]);
      Oacc[3] = MFMA16(pa[ks], v3, Oacc[3]);
      lacc    = MFMA16(pa[ks], onesb, lacc);
    }
  }

  // lacc[r] = full row sum for q-row quad*4+r; O store in A-FRAG-MAJOR
  // (proj GEMM's A-path).
  const int b = bh / 12, h = bh - (bh / 12) * 12;
  #pragma unroll
  for (int r = 0; r < 4; r++) {
    float inv = 1.0f / lacc[r];
    int np  = q0 + wave * 16 + quad * 4 + r;
    int M16 = b * 64 + (np >> 4);
    int l16m = np & 15;
    #pragma unroll
    for (int j = 0; j < 4; j++) {
      int col = h * 64 + j * 16 + l16;
      int kb2 = col >> 5;
      int qc  = (col >> 3) & 3;
      size_t idx = ((size_t)(kb2 * 512 + M16) << 9) +
                   ((qc * 16 + l16m) << 3) + (l16 & 7);
      of[idx] = f2bf(Oacc[j][r] * inv);
    }
  }
}

// ---------------------------------------------------------------------------
extern "C" void kernel_launch(void* const* d_in, const int* in_sizes, int n_in,
                              void* d_out, int out_size, void* d_ws, size_t ws_size,
                              hipStream_t stream) {
  const float* x      = (const float*)d_in[0];
  const float* w_qkv  = (const float*)d_in[1];
  const float* b_qkv  = (const float*)d_in[2];
  const float* w_proj = (const float*)d_in[3];
  const float* b_proj = (const float*)d_in[4];
  const float* q_a    = (const float*)d_in[5];
  const float* q_b    = (const float*)d_in[6];
  const float* k_a    = (const float*)d_in[7];
  const float* k_b    = (const float*)d_in[8];
  const float* v_a    = (const float*)d_in[9];
  const float* v_b    = (const float*)d_in[10];
  const float* o_a    = (const float*)d_in[11];
  const float* o_b    = (const float*)d_in[12];

  char* ws = (char*)d_ws;
  unsigned short* wqkv_eff  = (unsigned short*)(ws + 0);          // 3,538,944
  unsigned short* wproj_eff = (unsigned short*)(ws + 3538944);    // 1,179,648
  unsigned short* xf        = (unsigned short*)(ws + 4718592);    // 12,582,912 (A-frag-major; reused as of)
  unsigned short* qd        = (unsigned short*)(ws + 17301504);   // 12,582,912
  unsigned short* kd        = (unsigned short*)(ws + 29884416);   // 12,582,912
  unsigned short* vtd       = (unsigned short*)(ws + 42467328);   // 12,582,912 (end 55,050,240)
  unsigned short* of        = xf;  // xf dead after QKV GEMM

  prep<<<dim3(6144 + 9216), dim3(256), 0, stream>>>(
      x, w_qkv, w_proj, q_a, q_b, k_a, k_b, v_a, v_b, o_a, o_b,
      xf, wqkv_eff, wproj_eff);

  gemm_bt<96><<<dim3(64, 24), dim3(256), 0, stream>>>(
      xf, wqkv_eff, b_qkv, qd, kd, vtd, nullptr, 768, 2304, 0);

  attn<<<dim3(96, 16), dim3(256), 0, stream>>>(qd, kd, vtd, of);

  gemm_bt<64><<<dim3(64, 12), dim3(256), 0, stream>>>(
      of, wproj_eff, b_proj, nullptr, nullptr, nullptr, (float*)d_out, 768, 768, 1);
}